// Round 1
// baseline (174.026 us; speedup 1.0000x reference)
//
#include <hip/hip_runtime.h>

// out[l, k] = sum_{s : Q[items[l], s] == 1} E[user, s, k]
// SKILL_NUM = 256, K_HIDDEN = 128 fixed; L from in_sizes.
//
// One wave per sequence position; lane owns output cols {2*lane, 2*lane+1}.
// v3: instead of a serial 2-deep bit-scan over the ballot masks (13 exposed
// L2 round trips/wave), compact the active skill indices into a per-wave
// u8 list in LDS (ballot + popcount-prefix, fully parallel), then walk the
// list 8 skills per iteration: 8 global_load_dwordx2 in flight before the
// first dependent add -> ~4 L2 round trips per wave total.
// Bytes past n in the list are uninitialized LDS but any u8 is a valid
// skill index (<256), so the tail batch issues all 8 loads and just masks
// the adds -- no short serial remainder loop.

#define SKILL_NUM 256
#define K_HIDDEN  128

__global__ __launch_bounds__(256) void item_emb_kernel(
    const int*   __restrict__ user_p,   // [1]
    const float* __restrict__ Q,        // [N_ITEMS, 256]
    const int*   __restrict__ items,    // [L]
    const float* __restrict__ E_all,    // [USER_NUM, 256, 128]
    float*       __restrict__ out,      // [L, 128]
    int L)
{
    __shared__ __align__(8) unsigned char sidx[4][SKILL_NUM]; // 1 KB total

    const int wave = threadIdx.x >> 6;
    const int lane = threadIdx.x & 63;
    const int l    = blockIdx.x * 4 + wave;
    const bool valid = (l < L);

    const float2* __restrict__ E2 = (const float2*)(
        E_all + (size_t)user_p[0] * (SKILL_NUM * K_HIDDEN));

    // ---- build compact active-skill list (parallel, no serial bit scan) ----
    int n = 0;
    if (valid) {
        const int item = items[l];                          // wave-uniform
        // one dwordx4 per lane covers the whole 256-float Q row:
        // lane owns skills {4*lane .. 4*lane+3}
        const float4 qv = ((const float4*)(Q + (size_t)item * SKILL_NUM))[lane];
        const unsigned long long m0 = __ballot(qv.x != 0.0f);
        const unsigned long long m1 = __ballot(qv.y != 0.0f);
        const unsigned long long m2 = __ballot(qv.z != 0.0f);
        const unsigned long long m3 = __ballot(qv.w != 0.0f);
        const int c0 = __popcll(m0), c1 = __popcll(m1), c2 = __popcll(m2);
        const unsigned long long below = (1ull << lane) - 1ull;
        n = c0 + c1 + c2 + __popcll(m3);
        if (qv.x != 0.0f) sidx[wave][           __popcll(m0 & below)] = (unsigned char)(4*lane+0);
        if (qv.y != 0.0f) sidx[wave][c0       + __popcll(m1 & below)] = (unsigned char)(4*lane+1);
        if (qv.z != 0.0f) sidx[wave][c0+c1    + __popcll(m2 & below)] = (unsigned char)(4*lane+2);
        if (qv.w != 0.0f) sidx[wave][c0+c1+c2 + __popcll(m3 & below)] = (unsigned char)(4*lane+3);
    }
    __syncthreads();           // orders per-wave ds_write -> ds_read; uniform
    if (!valid) return;

    // ---- walk the list, 8 skills per batch, all 8 loads in flight ----
    float ax0 = 0.f, ay0 = 0.f, ax1 = 0.f, ay1 = 0.f;

    const unsigned long long* packp = (const unsigned long long*)&sidx[wave][0];
    const int nb = (n + 7) >> 3;
    for (int b = 0; b < nb; ++b) {
        const unsigned long long pack = packp[b];           // 8B LDS broadcast
        // indices are wave-uniform: hoist to SGPRs so loads use saddr form
        const int s0 = __builtin_amdgcn_readfirstlane((int)( pack        & 0xff));
        const int s1 = __builtin_amdgcn_readfirstlane((int)((pack >>  8) & 0xff));
        const int s2 = __builtin_amdgcn_readfirstlane((int)((pack >> 16) & 0xff));
        const int s3 = __builtin_amdgcn_readfirstlane((int)((pack >> 24) & 0xff));
        const int s4 = __builtin_amdgcn_readfirstlane((int)((pack >> 32) & 0xff));
        const int s5 = __builtin_amdgcn_readfirstlane((int)((pack >> 40) & 0xff));
        const int s6 = __builtin_amdgcn_readfirstlane((int)((pack >> 48) & 0xff));
        const int s7 = __builtin_amdgcn_readfirstlane((int)((pack >> 56) & 0xff));
        const float2 a0 = E2[(size_t)(s0 * 64) + lane];     // 8 dwordx2 loads,
        const float2 a1 = E2[(size_t)(s1 * 64) + lane];     // all issued before
        const float2 a2 = E2[(size_t)(s2 * 64) + lane];     // any dependent add
        const float2 a3 = E2[(size_t)(s3 * 64) + lane];
        const float2 a4 = E2[(size_t)(s4 * 64) + lane];
        const float2 a5 = E2[(size_t)(s5 * 64) + lane];
        const float2 a6 = E2[(size_t)(s6 * 64) + lane];
        const float2 a7 = E2[(size_t)(s7 * 64) + lane];
        const int base = b << 3;
        if (base + 8 <= n) {                                // wave-uniform
            ax0 += a0.x + a1.x;  ay0 += a0.y + a1.y;
            ax1 += a2.x + a3.x;  ay1 += a2.y + a3.y;
            ax0 += a4.x + a5.x;  ay0 += a4.y + a5.y;
            ax1 += a6.x + a7.x;  ay1 += a6.y + a7.y;
        } else {                                            // tail: mask adds
            const int r = n - base;                         // 1..7
            if (r > 0) { ax0 += a0.x; ay0 += a0.y; }
            if (r > 1) { ax0 += a1.x; ay0 += a1.y; }
            if (r > 2) { ax1 += a2.x; ay1 += a2.y; }
            if (r > 3) { ax1 += a3.x; ay1 += a3.y; }
            if (r > 4) { ax0 += a4.x; ay0 += a4.y; }
            if (r > 5) { ax0 += a5.x; ay0 += a5.y; }
            if (r > 6) { ax1 += a6.x; ay1 += a6.y; }
        }
    }

    float2 rr;
    rr.x = ax0 + ax1;
    rr.y = ay0 + ay1;
    ((float2*)out)[(size_t)l * 64 + lane] = rr;             // dwordx2 store
}

extern "C" void kernel_launch(void* const* d_in, const int* in_sizes, int n_in,
                              void* d_out, int out_size, void* d_ws, size_t ws_size,
                              hipStream_t stream) {
    const int*   user_p = (const int*)  d_in[0];
    const float* Q      = (const float*)d_in[1];
    const int*   items  = (const int*)  d_in[2];
    const float* E_all  = (const float*)d_in[3];
    float*       out    = (float*)      d_out;

    const int L = in_sizes[2];                 // SEQ_LEN (8192)
    const int blocks = (L + 3) / 4;            // 4 positions (waves) per block

    item_emb_kernel<<<blocks, 256, 0, stream>>>(user_p, Q, items, E_all, out, L);
}